// Round 1
// baseline (467.859 us; speedup 1.0000x reference)
//
#include <hip/hip_runtime.h>
#include <math.h>

#define LSEQ 2048
#define NB 2
#define HDIM 1024
#define NKV 128          // 2*HEAD_SIZE
#define MALL (NB*LSEQ)   // 4096

// ---------------- K1: seq_out partials = inputs @ Wp (K split in 2) --------
// grid (4, 64): x = {ntile(2) x split(2)}, y = m-tile. 256 threads, 64x64 tile,
// micro 4x4 per thread, K-chunk 32.
__global__ __launch_bounds__(256) void k1_gemm(const float* __restrict__ A,
                                               const float* __restrict__ Wp,
                                               float* __restrict__ Cp) {
    const int nt    = blockIdx.x & 1;
    const int split = blockIdx.x >> 1;
    const int m0 = blockIdx.y * 64;
    const int n0 = nt * 64;
    __shared__ float As[32][68];   // [k][m], pad 68 keeps float4 reads 16B-aligned
    __shared__ float Bs[32][64];   // [k][n]
    const int tid = threadIdx.x;
    const int tm = tid & 15;       // m quad
    const int tn = tid >> 4;       // n quad
    float acc[4][4] = {};
    for (int kc = 0; kc < 16; ++kc) {
        const int k0 = split*512 + kc*32;
        #pragma unroll
        for (int p = 0; p < 2; ++p) {
            int idx = tid + 256*p;          // 0..511
            int row = idx >> 3, kq = idx & 7;
            float4 a = *(const float4*)(A + (size_t)(m0+row)*HDIM + k0 + 4*kq);
            As[4*kq+0][row] = a.x;
            As[4*kq+1][row] = a.y;
            As[4*kq+2][row] = a.z;
            As[4*kq+3][row] = a.w;
        }
        #pragma unroll
        for (int p = 0; p < 2; ++p) {
            int idx = tid + 256*p;
            int r = idx >> 4, c = idx & 15;
            *(float4*)(&Bs[r][4*c]) = *(const float4*)(Wp + (size_t)(k0+r)*NKV + n0 + 4*c);
        }
        __syncthreads();
        #pragma unroll
        for (int kk = 0; kk < 32; ++kk) {
            float4 av = *(const float4*)(&As[kk][4*tm]);
            float4 bv = *(const float4*)(&Bs[kk][4*tn]);
            float aa[4] = {av.x, av.y, av.z, av.w};
            float bb[4] = {bv.x, bv.y, bv.z, bv.w};
            #pragma unroll
            for (int i = 0; i < 4; ++i)
                #pragma unroll
                for (int j = 0; j < 4; ++j)
                    acc[i][j] = fmaf(aa[i], bb[j], acc[i][j]);
        }
        __syncthreads();
    }
    float* outp = Cp + (size_t)split*MALL*NKV;
    #pragma unroll
    for (int i = 0; i < 4; ++i) {
        float4 v = make_float4(acc[i][0], acc[i][1], acc[i][2], acc[i][3]);
        *(float4*)(outp + (size_t)(m0 + 4*tm + i)*NKV + n0 + 4*tn) = v;
    }
}

// ---------------- K2: sum K-splits (+bp), RoPE, bias = seq@Wq/2 ------------
// grid 4096 blocks x 64 threads (1 wave per row).
__global__ __launch_bounds__(64) void k2_rope_bias(const float* __restrict__ Cp,
        const float* __restrict__ bp, const float* __restrict__ Wq,
        const float* __restrict__ bq, float* __restrict__ qwout,
        float* __restrict__ kwout, float* __restrict__ biasQ,
        float* __restrict__ biasK) {
    const int row = blockIdx.x;         // 0..4095 (b*L + l)
    const int b = row >> 11;
    const int l = row & (LSEQ - 1);
    const int t = threadIdx.x;          // 0..63 ; lane t owns dims (2t, 2t+1)
    const float* r0 = Cp + (size_t)row*NKV;
    const float* r1 = r0 + (size_t)MALL*NKV;
    float x0 = r0[2*t]   + r1[2*t]   + bp[2*t];
    float x1 = r0[2*t+1] + r1[2*t+1] + bp[2*t+1];
    // RoPE: lanes 0..31 -> q (dims 0..63), lanes 32..63 -> k (dims 64..127)
    const int p = t & 31;               // pair index within head
    float inv = exp2f(-0.41524101186098287f * (float)p);  // 10000^(-p/32)
    float ang = (float)l * inv;
    float sn = sinf(ang), cs = cosf(ang);
    float y0 = x0*cs - x1*sn;
    float y1 = x1*cs + x0*sn;
    float* dst = (t < 32) ? (qwout + (size_t)row*64) : (kwout + (size_t)row*64);
    dst[2*p]   = y0;
    dst[2*p+1] = y1;
    // bias: 24 dot-products of (pre-RoPE) row with Wq columns, wave-reduced
    float res = 0.f;
    for (int j = 0; j < 24; ++j) {
        float part = fmaf(x0, Wq[(2*t)*24 + j], x1 * Wq[(2*t+1)*24 + j]);
        #pragma unroll
        for (int off = 32; off > 0; off >>= 1)
            part += __shfl_xor(part, off);
        if (t == j) res = part;
    }
    if (t < 24) {
        float v = (res + bq[t]) * 0.5f;
        int h = t >> 1;
        float* bb = (t & 1) ? biasK : biasQ;
        bb[((size_t)b*12 + h)*LSEQ + l] = v;
    }
}

// ---------------- K3: scores + bias + mask + tril, 12-head fan-out ---------
// grid (32, 64, 2): x = n-tile(64), y = m-tile(32), z = b. 256 threads.
// Thread (tm=tid>>6, tn=tid&63): kw[n0+tn] in regs, 8 m-rows via LDS broadcast.
__global__ __launch_bounds__(256) void k3_scores(const float* __restrict__ qw,
        const float* __restrict__ kwv, const float* __restrict__ biasQ,
        const float* __restrict__ biasK, const int* __restrict__ mask,
        float* __restrict__ out) {
    const int n0 = blockIdx.x * 64;
    const int m0 = blockIdx.y * 32;
    const int b  = blockIdx.z;
    const int tid = threadIdx.x;
    const int tn = tid & 63;
    const int tm = tid >> 6;            // 0..3, each handles 8 rows
    __shared__ float qlds[32*64];
    __shared__ float bQ[12][32];
    __shared__ float bK[12][64];
    __shared__ float mM[32];
    __shared__ float mN[64];
    const size_t rowbase = (size_t)b * LSEQ;
    #pragma unroll
    for (int pld = 0; pld < 2; ++pld) {
        int idx = tid + 256*pld;        // 0..511 quads
        int r = idx >> 4, q = idx & 15;
        *(float4*)&qlds[r*64 + 4*q] =
            *(const float4*)(qw + (rowbase + m0 + r)*64 + 4*q);
    }
    for (int i = tid; i < 384; i += 256) {
        int h = i >> 5, m = i & 31;
        bQ[h][m] = biasQ[((size_t)b*12 + h)*LSEQ + m0 + m];
    }
    for (int i = tid; i < 768; i += 256) {
        int h = i >> 6, n = i & 63;
        bK[h][n] = biasK[((size_t)b*12 + h)*LSEQ + n0 + n];
    }
    if (tid < 32)       mM[tid]    = (mask[rowbase + m0 + tid] != 0) ? 1.f : 0.f;
    else if (tid < 96)  mN[tid-32] = (mask[rowbase + n0 + (tid-32)] != 0) ? 1.f : 0.f;
    // kw row for this thread's n, into registers (64 floats)
    float4 kr[16];
    const float4* kp = (const float4*)(kwv + (rowbase + n0 + tn)*64);
    #pragma unroll
    for (int j = 0; j < 16; ++j) kr[j] = kp[j];
    __syncthreads();

    const float4* q4 = (const float4*)qlds;
    float accv[8];
    #pragma unroll
    for (int i = 0; i < 8; ++i) {
        const int ml = tm*8 + i;
        float s = 0.f;
        #pragma unroll
        for (int j = 0; j < 16; ++j) {
            float4 qv = q4[ml*16 + j];   // wave-uniform -> LDS broadcast
            s = fmaf(qv.x, kr[j].x, s);
            s = fmaf(qv.y, kr[j].y, s);
            s = fmaf(qv.z, kr[j].z, s);
            s = fmaf(qv.w, kr[j].w, s);
        }
        accv[i] = s * 0.125f;            // / sqrt(64)
    }
    const int n = n0 + tn;
    const float mn = mN[tn];
    float bk[12];
    #pragma unroll
    for (int h = 0; h < 12; ++h) bk[h] = bK[h][tn];
    #pragma unroll
    for (int i = 0; i < 8; ++i) {
        const int ml = tm*8 + i;
        const int m = m0 + ml;
        const float pen = (m > n) ? 1e12f : 0.f;
        const bool ok = (mM[ml] != 0.f) && (mn != 0.f);
        size_t off = (size_t)b*12*LSEQ*LSEQ + (size_t)m*LSEQ + n;
        #pragma unroll
        for (int h = 0; h < 12; ++h) {
            float v = accv[i] + bQ[h][ml] + bk[h];
            v = ok ? v : -INFINITY;
            v -= pen;                    // -inf stays -inf
            out[off + (size_t)h*LSEQ*LSEQ] = v;
        }
    }
}

extern "C" void kernel_launch(void* const* d_in, const int* in_sizes, int n_in,
                              void* d_out, int out_size, void* d_ws, size_t ws_size,
                              hipStream_t stream) {
    const float* inputs = (const float*)d_in[0];   // (2,2048,1024)
    const int*   mask   = (const int*)  d_in[1];   // (2,2048)
    const float* Wp     = (const float*)d_in[2];   // (1024,128)
    const float* bp     = (const float*)d_in[3];   // (128,)
    const float* Wq     = (const float*)d_in[4];   // (128,24)
    const float* bq     = (const float*)d_in[5];   // (24,)
    float* out = (float*)d_out;                    // (2,12,2048,2048)

    float* Cp  = (float*)d_ws;                     // 2 * 4096 * 128
    float* qwb = Cp  + (size_t)2*MALL*NKV;         // 4096 * 64
    float* kwb = qwb + (size_t)MALL*64;            // 4096 * 64
    float* bQ  = kwb + (size_t)MALL*64;            // 2*12*2048
    float* bK  = bQ  + (size_t)NB*12*LSEQ;         // 2*12*2048

    k1_gemm     <<<dim3(4, 64),     256, 0, stream>>>(inputs, Wp, Cp);
    k2_rope_bias<<<dim3(MALL),       64, 0, stream>>>(Cp, bp, Wq, bq, qwb, kwb, bQ, bK);
    k3_scores   <<<dim3(32, 64, 2), 256, 0, stream>>>(qwb, kwb, bQ, bK, mask, out);
}

// Round 2
// 465.878 us; speedup vs baseline: 1.0043x; 1.0043x over previous
//
#include <hip/hip_runtime.h>
#include <math.h>

#define LSEQ 2048
#define NB 2
#define HDIM 1024
#define NKV 128          // 2*HEAD_SIZE
#define MALL (NB*LSEQ)   // 4096
#define KSPLIT 4

// ---------------- K1: seq_out partials = inputs @ Wp (K split in 4) --------
// grid (8, 64): x = nt(2) + 2*split(4), y = m-tile. 256 threads, 64x64 tile,
// micro 4x4 per thread, K-chunk 32, 8 chunks per split.
__global__ __launch_bounds__(256) void k1_gemm(const float* __restrict__ A,
                                               const float* __restrict__ Wp,
                                               float* __restrict__ Cp) {
    const int nt    = blockIdx.x & 1;
    const int split = blockIdx.x >> 1;
    const int m0 = blockIdx.y * 64;
    const int n0 = nt * 64;
    __shared__ float As[32][68];   // [k][m], pad 68 keeps float4 reads 16B-aligned
    __shared__ float Bs[32][64];   // [k][n]
    const int tid = threadIdx.x;
    const int tm = tid & 15;       // m quad
    const int tn = tid >> 4;       // n quad
    float acc[4][4] = {};
    for (int kc = 0; kc < 8; ++kc) {
        const int k0 = split*256 + kc*32;
        #pragma unroll
        for (int p = 0; p < 2; ++p) {
            int idx = tid + 256*p;          // 0..511
            int row = idx >> 3, kq = idx & 7;
            float4 a = *(const float4*)(A + (size_t)(m0+row)*HDIM + k0 + 4*kq);
            As[4*kq+0][row] = a.x;
            As[4*kq+1][row] = a.y;
            As[4*kq+2][row] = a.z;
            As[4*kq+3][row] = a.w;
        }
        #pragma unroll
        for (int p = 0; p < 2; ++p) {
            int idx = tid + 256*p;
            int r = idx >> 4, c = idx & 15;
            *(float4*)(&Bs[r][4*c]) = *(const float4*)(Wp + (size_t)(k0+r)*NKV + n0 + 4*c);
        }
        __syncthreads();
        #pragma unroll
        for (int kk = 0; kk < 32; ++kk) {
            float4 av = *(const float4*)(&As[kk][4*tm]);
            float4 bv = *(const float4*)(&Bs[kk][4*tn]);
            float aa[4] = {av.x, av.y, av.z, av.w};
            float bb[4] = {bv.x, bv.y, bv.z, bv.w};
            #pragma unroll
            for (int i = 0; i < 4; ++i)
                #pragma unroll
                for (int j = 0; j < 4; ++j)
                    acc[i][j] = fmaf(aa[i], bb[j], acc[i][j]);
        }
        __syncthreads();
    }
    float* outp = Cp + (size_t)split*MALL*NKV;
    #pragma unroll
    for (int i = 0; i < 4; ++i) {
        float4 v = make_float4(acc[i][0], acc[i][1], acc[i][2], acc[i][3]);
        *(float4*)(outp + (size_t)(m0 + 4*tm + i)*NKV + n0 + 4*tn) = v;
    }
}

// ---------------- K2: sum K-splits (+bp), RoPE, bias = seq@Wq/2 ------------
// grid 4096 blocks x 64 threads (1 wave per row).
__global__ __launch_bounds__(64) void k2_rope_bias(const float* __restrict__ Cp,
        const float* __restrict__ bp, const float* __restrict__ Wq,
        const float* __restrict__ bq, float* __restrict__ qwout,
        float* __restrict__ kwout, float* __restrict__ biasQ,
        float* __restrict__ biasK) {
    const int row = blockIdx.x;         // 0..4095 (b*L + l)
    const int b = row >> 11;
    const int l = row & (LSEQ - 1);
    const int t = threadIdx.x;          // 0..63 ; lane t owns dims (2t, 2t+1)
    float x0 = bp[2*t], x1 = bp[2*t+1];
    #pragma unroll
    for (int s = 0; s < KSPLIT; ++s) {
        const float* r = Cp + (size_t)s*MALL*NKV + (size_t)row*NKV;
        x0 += r[2*t];
        x1 += r[2*t+1];
    }
    // RoPE: lanes 0..31 -> q (dims 0..63), lanes 32..63 -> k (dims 64..127)
    const int p = t & 31;               // pair index within head
    float inv = exp2f(-0.41524101186098287f * (float)p);  // 10000^(-p/32)
    float ang = (float)l * inv;
    float sn = sinf(ang), cs = cosf(ang);
    float y0 = x0*cs - x1*sn;
    float y1 = x1*cs + x0*sn;
    float* dst = (t < 32) ? (qwout + (size_t)row*64) : (kwout + (size_t)row*64);
    dst[2*p]   = y0;
    dst[2*p+1] = y1;
    // bias: 24 dot-products of (pre-RoPE) row with Wq columns, wave-reduced
    float res = 0.f;
    for (int j = 0; j < 24; ++j) {
        float part = fmaf(x0, Wq[(2*t)*24 + j], x1 * Wq[(2*t+1)*24 + j]);
        #pragma unroll
        for (int off = 32; off > 0; off >>= 1)
            part += __shfl_xor(part, off);
        if (t == j) res = part;
    }
    if (t < 24) {
        float v = (res + bq[t]) * 0.5f;
        int h = t >> 1;
        float* bb = (t & 1) ? biasK : biasQ;
        bb[((size_t)b*12 + h)*LSEQ + l] = v;
    }
}

// ---------------- K3 v2: scores + bias + mask + tril, 12-head fan-out ------
// grid (512, 2): x = m-tile (4 rows), y = b. 256 threads.
// Thread: g = tid>>7 owns m rows {2g,2g+1} (q in 128 VGPRs), nl = tid&127.
// Loop 16 chunks of 128 n: stage kw chunk to LDS coalesced, dot from LDS,
// fan out 12 heads with nontemporal stores (out > L3 -> don't pollute it).
__global__ __launch_bounds__(256, 2) void k3_scores(const float* __restrict__ qw,
        const float* __restrict__ kwv, const float* __restrict__ biasQ,
        const float* __restrict__ biasK, const int* __restrict__ mask,
        float* __restrict__ out) {
    const int m0 = blockIdx.x * 4;
    const int b  = blockIdx.y;
    const int tid = threadIdx.x;
    const int nl = tid & 127;
    const int g  = tid >> 7;            // 0/1 -> m rows 2g, 2g+1
    __shared__ float kws[128 * 68];     // pad 68: word off 4*(n+j) mod 32 -> even banks

    const size_t rowbase = (size_t)b * LSEQ;
    const int mA = m0 + 2*g, mB = mA + 1;

    float4 q0[16], q1[16];
    {
        const float4* qp0 = (const float4*)(qw + (rowbase + mA)*64);
        const float4* qp1 = (const float4*)(qw + (rowbase + mB)*64);
        #pragma unroll
        for (int j = 0; j < 16; ++j) { q0[j] = qp0[j]; q1[j] = qp1[j]; }
    }
    float bq0[12], bq1[12];
    #pragma unroll
    for (int h = 0; h < 12; ++h) {
        const float* bqp = biasQ + ((size_t)b*12 + h)*LSEQ;
        bq0[h] = bqp[mA];
        bq1[h] = bqp[mB];
    }
    const bool okmA = mask[rowbase + mA] != 0;
    const bool okmB = mask[rowbase + mB] != 0;
    const size_t outbase = (size_t)b * 12 * LSEQ * LSEQ;

    for (int c = 0; c < 16; ++c) {
        const int nbase = c * 128;
        __syncthreads();                 // guard kws against previous chunk's readers
        #pragma unroll
        for (int p = 0; p < 8; ++p) {
            int f4 = tid + 256*p;        // 0..2047 float4-chunks
            int r = f4 >> 4, q16 = f4 & 15;
            float4 v = *(const float4*)(kwv + (rowbase + nbase + r)*64 + 4*q16);
            *(float4*)(&kws[r*68 + 4*q16]) = v;
        }
        __syncthreads();

        const int n = nbase + nl;
        float acc0 = 0.f, acc1 = 0.f;
        const float4* kr = (const float4*)(&kws[nl * 68]);  // 272B stride: 16B aligned
        #pragma unroll
        for (int j = 0; j < 16; ++j) {
            float4 kv = kr[j];
            acc0 = fmaf(q0[j].x, kv.x, acc0);
            acc0 = fmaf(q0[j].y, kv.y, acc0);
            acc0 = fmaf(q0[j].z, kv.z, acc0);
            acc0 = fmaf(q0[j].w, kv.w, acc0);
            acc1 = fmaf(q1[j].x, kv.x, acc1);
            acc1 = fmaf(q1[j].y, kv.y, acc1);
            acc1 = fmaf(q1[j].z, kv.z, acc1);
            acc1 = fmaf(q1[j].w, kv.w, acc1);
        }
        acc0 *= 0.125f;                  // / sqrt(64)
        acc1 *= 0.125f;

        const bool okn = mask[rowbase + n] != 0;
        const float penA = (mA > n) ? 1e12f : 0.f;
        const float penB = (mB > n) ? 1e12f : 0.f;
        const bool okA = okmA && okn;
        const bool okB = okmB && okn;
        size_t offA = outbase + (size_t)mA * LSEQ + n;
        const float* bkp = biasK + (size_t)b*12*LSEQ + n;
        #pragma unroll
        for (int h = 0; h < 12; ++h) {
            float bk = bkp[(size_t)h * LSEQ];
            float v0 = acc0 + bq0[h] + bk;
            v0 = okA ? v0 : -INFINITY;
            v0 -= penA;
            float v1 = acc1 + bq1[h] + bk;
            v1 = okB ? v1 : -INFINITY;
            v1 -= penB;
            __builtin_nontemporal_store(v0, &out[offA + (size_t)h*LSEQ*LSEQ]);
            __builtin_nontemporal_store(v1, &out[offA + LSEQ + (size_t)h*LSEQ*LSEQ]);
        }
    }
}

extern "C" void kernel_launch(void* const* d_in, const int* in_sizes, int n_in,
                              void* d_out, int out_size, void* d_ws, size_t ws_size,
                              hipStream_t stream) {
    const float* inputs = (const float*)d_in[0];   // (2,2048,1024)
    const int*   mask   = (const int*)  d_in[1];   // (2,2048)
    const float* Wp     = (const float*)d_in[2];   // (1024,128)
    const float* bp     = (const float*)d_in[3];   // (128,)
    const float* Wq     = (const float*)d_in[4];   // (128,24)
    const float* bq     = (const float*)d_in[5];   // (24,)
    float* out = (float*)d_out;                    // (2,12,2048,2048)

    float* Cp  = (float*)d_ws;                     // KSPLIT * 4096 * 128
    float* qwb = Cp  + (size_t)KSPLIT*MALL*NKV;    // 4096 * 64
    float* kwb = qwb + (size_t)MALL*64;            // 4096 * 64
    float* bQ  = kwb + (size_t)MALL*64;            // 2*12*2048
    float* bK  = bQ  + (size_t)NB*12*LSEQ;         // 2*12*2048

    k1_gemm     <<<dim3(8, 64),   256, 0, stream>>>(inputs, Wp, Cp);
    k2_rope_bias<<<dim3(MALL),     64, 0, stream>>>(Cp, bp, Wq, bq, qwb, kwb, bQ, bK);
    k3_scores   <<<dim3(512, 2), 256, 0, stream>>>(qwb, kwb, bQ, bK, mask, out);
}